// Round 1
// baseline (112.416 us; speedup 1.0000x reference)
//
#include <hip/hip_runtime.h>
#include <math.h>

// Problem constants (from reference): noises [L=12, N=4096, D=16] fp32.
// Loss factorizes: ce.sum() = sum_l sum_d (sum_i p)(sum_j log_q); diag is a
// per-row dot. Single pass over 3 MB input, no N x N matrix.
#define LAYERS 12
#define NROWS  4096
#define DDIM   16
#define BLOCK  256
#define NBLK   ((LAYERS * NROWS) / BLOCK)   // 192 blocks, 16 per layer
#define BLK_PER_LAYER (NROWS / BLOCK)       // 16
#define PART_STRIDE 33                      // 16 sumP + 16 sumLQ + 1 diag

__device__ __forceinline__ float wave_red(float v) {
    #pragma unroll
    for (int off = 32; off > 0; off >>= 1)
        v += __shfl_down(v, off, 64);
    return v;
}

__global__ __launch_bounds__(BLOCK)
void moe_loss_pass1(const float* __restrict__ x, float* __restrict__ part) {
    const int r = blockIdx.x * BLOCK + threadIdx.x;   // global row, exact fit
    const float4* x4 = (const float4*)x;
    const int r4 = r * 4;

    float v[DDIM];
    float4 a;
    a = x4[r4 + 0]; v[0]  = a.x; v[1]  = a.y; v[2]  = a.z; v[3]  = a.w;
    a = x4[r4 + 1]; v[4]  = a.x; v[5]  = a.y; v[6]  = a.z; v[7]  = a.w;
    a = x4[r4 + 2]; v[8]  = a.x; v[9]  = a.y; v[10] = a.z; v[11] = a.w;
    a = x4[r4 + 3]; v[12] = a.x; v[13] = a.y; v[14] = a.z; v[15] = a.w;

    // softmax over 16 elements
    float m = v[0];
    #pragma unroll
    for (int d = 1; d < DDIM; d++) m = fmaxf(m, v[d]);
    float e[DDIM];
    float s = 0.f;
    #pragma unroll
    for (int d = 0; d < DDIM; d++) { e[d] = __expf(v[d] - m); s += e[d]; }
    const float inv = __frcp_rn(s);

    float p[DDIM], lq[DDIM];
    float diag = 0.f;
    #pragma unroll
    for (int d = 0; d < DDIM; d++) {
        p[d]  = e[d] * inv;
        lq[d] = __logf(p[d] + 1e-9f);
        diag += p[d] * lq[d];
    }

    // block reduction of 33 values (16 sumP, 16 sumLQ, 1 diag)
    __shared__ float lds[BLOCK / 64][PART_STRIDE];
    const int wave = threadIdx.x >> 6;
    const int lane = threadIdx.x & 63;

    #pragma unroll
    for (int d = 0; d < DDIM; d++) {
        float t = wave_red(p[d]);
        if (lane == 0) lds[wave][d] = t;
    }
    #pragma unroll
    for (int d = 0; d < DDIM; d++) {
        float t = wave_red(lq[d]);
        if (lane == 0) lds[wave][DDIM + d] = t;
    }
    {
        float t = wave_red(diag);
        if (lane == 0) lds[wave][32] = t;
    }
    __syncthreads();

    if (threadIdx.x < PART_STRIDE) {
        float t = lds[0][threadIdx.x] + lds[1][threadIdx.x]
                + lds[2][threadIdx.x] + lds[3][threadIdx.x];
        part[blockIdx.x * PART_STRIDE + threadIdx.x] = t;
    }
}

__global__ __launch_bounds__(BLOCK)
void moe_loss_pass2(const float* __restrict__ part, float* __restrict__ out) {
    __shared__ double sP[LAYERS][DDIM];
    __shared__ double sLQ[LAYERS][DDIM];
    __shared__ double dg[LAYERS];
    const int tid = threadIdx.x;

    if (tid < LAYERS * DDIM) {
        const int l = tid / DDIM, d = tid % DDIM;
        double a = 0.0, b = 0.0;
        for (int bb = 0; bb < BLK_PER_LAYER; bb++) {
            const float* pp = part + (l * BLK_PER_LAYER + bb) * PART_STRIDE;
            a += (double)pp[d];
            b += (double)pp[DDIM + d];
        }
        sP[l][d] = a; sLQ[l][d] = b;
    }
    if (tid < LAYERS) {
        double a = 0.0;
        for (int bb = 0; bb < BLK_PER_LAYER; bb++)
            a += (double)part[(tid * BLK_PER_LAYER + bb) * PART_STRIDE + 32];
        dg[tid] = a;
    }
    __syncthreads();

    if (tid == 0) {
        double ce = 0.0, dtot = 0.0, aux2 = 0.0;
        for (int l = 0; l < LAYERS; l++) {
            double S = 0.0;
            for (int d = 0; d < DDIM; d++) { ce += sP[l][d] * sLQ[l][d]; S += sP[l][d]; }
            dtot += dg[l];
            double t = 0.0;
            for (int d = 0; d < DDIM; d++)
                t += log(sP[l][d] / S + 1e-8);
            aux2 += -t / (double)DDIM;
        }
        const double aux1 = (ce - dtot) / (2.0 * LAYERS);
        const double res  = 0.01 * (1.0 * aux1 + aux2 / (double)LAYERS);
        out[0] = (float)res;
    }
}

extern "C" void kernel_launch(void* const* d_in, const int* in_sizes, int n_in,
                              void* d_out, int out_size, void* d_ws, size_t ws_size,
                              hipStream_t stream) {
    const float* noises = (const float*)d_in[0];
    float* part = (float*)d_ws;          // 192*33*4 = 25,344 B scratch
    float* out  = (float*)d_out;
    hipLaunchKernelGGL(moe_loss_pass1, dim3(NBLK), dim3(BLOCK), 0, stream, noises, part);
    hipLaunchKernelGGL(moe_loss_pass2, dim3(1), dim3(BLOCK), 0, stream, part, out);
}

// Round 2
// 69.088 us; speedup vs baseline: 1.6272x; 1.6272x over previous
//
#include <hip/hip_runtime.h>
#include <math.h>

// noises [L=12, N=4096, D=16] fp32. Loss factorizes:
//   ce.sum()  = sum_l sum_d (sum_i p[l,i,d]) * (sum_j log_q[l,j,d])
//   diag_sum  = sum_{l,i,d} p*log_q   (per-row dot)
//   aux2 needs only sum_i p[l,i,d]
// -> one pass over 3 MB, 33 partials per block, last-block finalize.
#define LAYERS 12
#define NROWS  4096
#define DDIM   16
#define BLOCK  256
#define ROWS_PER_THREAD 4
#define ROWS_PER_BLOCK  (BLOCK * ROWS_PER_THREAD)      // 1024
#define BLK_PER_LAYER   (NROWS / ROWS_PER_BLOCK)       // 4
#define NBLK            (LAYERS * BLK_PER_LAYER)       // 48 blocks
#define PART 33                                        // 16 sumP + 16 sumLQ + 1 diag

__device__ __forceinline__ float wave_red(float v) {
    #pragma unroll
    for (int off = 32; off > 0; off >>= 1)
        v += __shfl_down(v, off, 64);
    return v;
}

__global__ __launch_bounds__(BLOCK)
void moe_loss_fused(const float* __restrict__ x, float* __restrict__ part,
                    unsigned int* __restrict__ counter, float* __restrict__ out) {
    const int tid = threadIdx.x;
    const int b   = blockIdx.x;                        // block b covers rows [b*1024, b*1024+1024), one layer
    const int wave = tid >> 6;
    const int lane = tid & 63;

    float sp[DDIM], slq[DDIM];
    float diag = 0.f;
    #pragma unroll
    for (int d = 0; d < DDIM; d++) { sp[d] = 0.f; slq[d] = 0.f; }

    const float4* x4 = (const float4*)x;
    const int base_row = b * ROWS_PER_BLOCK;

    #pragma unroll
    for (int k = 0; k < ROWS_PER_THREAD; k++) {
        const int r4 = (base_row + k * BLOCK + tid) * 4;
        float v[DDIM]; float4 a;
        a = x4[r4 + 0]; v[0]  = a.x; v[1]  = a.y; v[2]  = a.z; v[3]  = a.w;
        a = x4[r4 + 1]; v[4]  = a.x; v[5]  = a.y; v[6]  = a.z; v[7]  = a.w;
        a = x4[r4 + 2]; v[8]  = a.x; v[9]  = a.y; v[10] = a.z; v[11] = a.w;
        a = x4[r4 + 3]; v[12] = a.x; v[13] = a.y; v[14] = a.z; v[15] = a.w;

        float m = v[0];
        #pragma unroll
        for (int d = 1; d < DDIM; d++) m = fmaxf(m, v[d]);
        float e[DDIM], s = 0.f;
        #pragma unroll
        for (int d = 0; d < DDIM; d++) { e[d] = __expf(v[d] - m); s += e[d]; }
        const float inv = __frcp_rn(s);
        #pragma unroll
        for (int d = 0; d < DDIM; d++) {
            const float p  = e[d] * inv;
            const float lq = __logf(p + 1e-9f);
            sp[d]  += p;
            slq[d] += lq;
            diag   += p * lq;
        }
    }

    // block-reduce 33 values -> part[b*33 .. b*33+32]
    __shared__ float lds[BLOCK / 64][PART];
    #pragma unroll
    for (int d = 0; d < DDIM; d++) {
        float t = wave_red(sp[d]);
        if (lane == 0) lds[wave][d] = t;
    }
    #pragma unroll
    for (int d = 0; d < DDIM; d++) {
        float t = wave_red(slq[d]);
        if (lane == 0) lds[wave][DDIM + d] = t;
    }
    {
        float t = wave_red(diag);
        if (lane == 0) lds[wave][32] = t;
    }
    __syncthreads();
    if (tid < PART) {
        part[b * PART + tid] = lds[0][tid] + lds[1][tid] + lds[2][tid] + lds[3][tid];
    }

    // --- last-block-done handshake ---
    __threadfence();              // release our partials device-wide
    __syncthreads();
    __shared__ unsigned int s_ticket;
    if (tid == 0) s_ticket = atomicAdd(counter, 1u);   // device-scope by default
    __syncthreads();
    if (s_ticket != NBLK - 1) return;
    __threadfence();              // acquire: see all blocks' partials

    // --- finalize (one block, parallel float) ---
    __shared__ float sP[LAYERS][DDIM];
    const int l = tid / DDIM, d = tid % DDIM;
    float a = 0.f, bq = 0.f;
    if (tid < LAYERS * DDIM) {
        #pragma unroll
        for (int k = 0; k < BLK_PER_LAYER; k++) {
            const float* pp = part + (l * BLK_PER_LAYER + k) * PART;
            a  += pp[d];
            bq += pp[DDIM + d];
        }
        sP[l][d] = a;
    }
    __syncthreads();
    float ce_v = 0.f, lg_v = 0.f;
    if (tid < LAYERS * DDIM) {
        float S = 0.f;
        #pragma unroll
        for (int d2 = 0; d2 < DDIM; d2++) S += sP[l][d2];
        ce_v = a * bq;                         // contributes to ce.sum()
        lg_v = __logf(a / S + 1e-8f);          // contributes to aux2 (pm = a/S)
    }
    float dg_v = (tid < NBLK) ? part[tid * PART + 32] : 0.f;

    __shared__ float red[3][BLOCK / 64];
    float r0 = wave_red(ce_v), r1 = wave_red(lg_v), r2 = wave_red(dg_v);
    if (lane == 0) { red[0][wave] = r0; red[1][wave] = r1; red[2][wave] = r2; }
    __syncthreads();
    if (tid == 0) {
        const float ce = red[0][0] + red[0][1] + red[0][2] + red[0][3];
        const float lg = red[1][0] + red[1][1] + red[1][2] + red[1][3];
        const float dg = red[2][0] + red[2][1] + red[2][2] + red[2][3];
        const float aux1 = (ce - dg) / (2.0f * LAYERS);
        const float aux2 = (-lg / (float)DDIM) / (float)LAYERS;
        out[0] = 0.01f * (1.0f * aux1 + aux2);
    }
}

extern "C" void kernel_launch(void* const* d_in, const int* in_sizes, int n_in,
                              void* d_out, int out_size, void* d_ws, size_t ws_size,
                              hipStream_t stream) {
    const float* noises = (const float*)d_in[0];
    unsigned int* counter = (unsigned int*)d_ws;          // 4 B, zeroed below
    float* part = (float*)((char*)d_ws + 256);            // 48*33*4 = 6336 B
    float* out  = (float*)d_out;
    hipMemsetAsync(d_ws, 0, 256, stream);                 // zero the ticket counter
    hipLaunchKernelGGL(moe_loss_fused, dim3(NBLK), dim3(BLOCK), 0, stream,
                       noises, part, counter, out);
}